// Round 1
// baseline (662.889 us; speedup 1.0000x reference)
//
#include <hip/hip_runtime.h>

#define NN 100000
#define NE 1600000
#define F 64

// ---------------- kernels ----------------

__global__ void k_deg(const int* __restrict__ src, const int* __restrict__ dst,
                      float* __restrict__ deg_out, float* __restrict__ deg_in) {
    int e = blockIdx.x * blockDim.x + threadIdx.x;
    if (e < NE) {
        atomicAdd(&deg_out[src[e]], 1.0f);
        atomicAdd(&deg_in[dst[e]], 1.0f);
    }
}

__global__ void k_norm(const float* __restrict__ deg_out, const float* __restrict__ deg_in,
                       float* __restrict__ norm_out, float* __restrict__ norm_in) {
    int n = blockIdx.x * blockDim.x + threadIdx.x;
    if (n < NN) {
        float d_o = deg_out[n];
        float d_i = deg_in[n];
        norm_out[n] = (d_o > 0.0f) ? rsqrtf(d_o) : 1.0f;
        norm_in[n]  = (d_i > 0.0f) ? rsqrtf(d_i) : 1.0f;
    }
}

// layer-1 message scatter: agg1[dst] += x[src] * norm_out[src]
// one wave (64 lanes) per edge, lane = feature
__global__ void k_scatter1(const int* __restrict__ src, const int* __restrict__ dst,
                           const float* __restrict__ x, const float* __restrict__ norm_out,
                           float* __restrict__ agg1) {
    int t = blockIdx.x * 256 + threadIdx.x;
    int e = t >> 6;          // wave-uniform
    int f = t & 63;
    if (e < NE) {
        int s = src[e];
        int d = dst[e];
        float v = x[(size_t)s * F + f] * norm_out[s];
        atomicAdd(&agg1[(size_t)d * F + f], v);
    }
}

// fused: h1 = relu(norm_in * (agg1 @ W1) + b1);  z = norm_out * (h1 @ W2)
// block = 256 threads = 4 nodes x 64 output-features
__global__ void k_l1l2(const float* __restrict__ agg1,
                       const float* __restrict__ norm_in, const float* __restrict__ norm_out,
                       const float* __restrict__ W1, const float* __restrict__ b1,
                       const float* __restrict__ W2,
                       float* __restrict__ z) {
    __shared__ float sW1[64 * 64];
    __shared__ float srow[4][64];
    int tid = threadIdx.x;
    for (int i = tid; i < 64 * 64; i += 256) sW1[i] = W1[i];
    int ni = tid >> 6;       // wave index in block (wave-uniform)
    int j  = tid & 63;       // output feature
    int n  = blockIdx.x * 4 + ni;
    float rowv = (n < NN) ? agg1[(size_t)n * F + j] : 0.0f;
    srow[ni][j] = rowv;
    __syncthreads();
    if (n < NN) {
        float acc = 0.0f;
#pragma unroll
        for (int k = 0; k < 64; ++k)
            acc += srow[ni][k] * sW1[k * 64 + j];   // srow broadcast, sW1 conflict-free
        float h = acc * norm_in[n] + b1[j];
        h = fmaxf(h, 0.0f);
        float zv = h * W2[j];
        // 64-lane reduction
#pragma unroll
        for (int off = 32; off; off >>= 1) zv += __shfl_xor(zv, off, 64);
        if (j == 0) z[n] = zv * norm_out[n];
    }
}

// layer-2 scalar scatter: agg2[dst] += z[src]
__global__ void k_scatter2(const int* __restrict__ src, const int* __restrict__ dst,
                           const float* __restrict__ z, float* __restrict__ agg2) {
    int e = blockIdx.x * blockDim.x + threadIdx.x;
    if (e < NE) {
        atomicAdd(&agg2[dst[e]], z[src[e]]);
    }
}

__global__ void k_out(const float* __restrict__ agg2, const float* __restrict__ norm_in,
                      const float* __restrict__ b2, float* __restrict__ out) {
    int n = blockIdx.x * blockDim.x + threadIdx.x;
    if (n < NN) {
        float v = agg2[n] * norm_in[n] + b2[0];
        out[n] = 1.0f / (1.0f + expf(-v));
    }
}

// ---------------- launch ----------------

extern "C" void kernel_launch(void* const* d_in, const int* in_sizes, int n_in,
                              void* d_out, int out_size, void* d_ws, size_t ws_size,
                              hipStream_t stream) {
    const float* x   = (const float*)d_in[0];
    const int*   src = (const int*)d_in[1];
    const int*   dst = (const int*)d_in[2];
    const float* W1  = (const float*)d_in[3];
    const float* b1  = (const float*)d_in[4];
    const float* W2  = (const float*)d_in[5];
    const float* b2  = (const float*)d_in[6];
    float* out = (float*)d_out;

    // ws layout (floats): agg1[NN*F] | deg_out[NN] | deg_in[NN] | agg2[NN] | norm_out[NN] | norm_in[NN] | z[NN]
    float* ws       = (float*)d_ws;
    float* agg1     = ws;
    float* deg_out  = agg1 + (size_t)NN * F;
    float* deg_in   = deg_out + NN;
    float* agg2     = deg_in + NN;
    float* norm_out = agg2 + NN;
    float* norm_in  = norm_out + NN;
    float* z        = norm_in + NN;

    // zero the accumulated regions (agg1, deg_out, deg_in, agg2) — contiguous
    size_t zero_bytes = ((size_t)NN * F + 3 * (size_t)NN) * sizeof(float);
    hipMemsetAsync(d_ws, 0, zero_bytes, stream);

    k_deg<<<(NE + 255) / 256, 256, 0, stream>>>(src, dst, deg_out, deg_in);
    k_norm<<<(NN + 255) / 256, 256, 0, stream>>>(deg_out, deg_in, norm_out, norm_in);

    long long t1 = (long long)NE * 64;
    k_scatter1<<<(unsigned)((t1 + 255) / 256), 256, 0, stream>>>(src, dst, x, norm_out, agg1);

    k_l1l2<<<(NN + 3) / 4, 256, 0, stream>>>(agg1, norm_in, norm_out, W1, b1, W2, z);

    k_scatter2<<<(NE + 255) / 256, 256, 0, stream>>>(src, dst, z, agg2);

    k_out<<<(NN + 255) / 256, 256, 0, stream>>>(agg2, norm_in, b2, out);
}

// Round 2
// 418.199 us; speedup vs baseline: 1.5851x; 1.5851x over previous
//
#include <hip/hip_runtime.h>

#define NN 100000
#define NE 1600000
#define F 64

// ---------------- degree + norm ----------------

__global__ void k_deg(const int* __restrict__ src, const int* __restrict__ dst,
                      float* __restrict__ deg_out, float* __restrict__ deg_in) {
    int e = blockIdx.x * blockDim.x + threadIdx.x;
    if (e < NE) {
        atomicAdd(&deg_out[src[e]], 1.0f);
        atomicAdd(&deg_in[dst[e]], 1.0f);
    }
}

__global__ void k_norm(const float* __restrict__ deg_out, const float* __restrict__ deg_in,
                       float* __restrict__ norm_out, float* __restrict__ norm_in) {
    int n = blockIdx.x * blockDim.x + threadIdx.x;
    if (n < NN) {
        float d_o = deg_out[n];
        float d_i = deg_in[n];
        norm_out[n] = (d_o > 0.0f) ? rsqrtf(d_o) : 1.0f;
        norm_in[n]  = (d_i > 0.0f) ? rsqrtf(d_i) : 1.0f;
    }
}

// ---------------- CSR build: prefix sum of deg_in ----------------
// 1024 nodes per block

__global__ void k_bsum(const float* __restrict__ deg_in, float* __restrict__ bsum) {
    __shared__ float red[4];
    int base = blockIdx.x * 1024;
    float s = 0.0f;
    for (int i = threadIdx.x; i < 1024; i += 256) {
        int n = base + i;
        s += (n < NN) ? deg_in[n] : 0.0f;
    }
#pragma unroll
    for (int off = 32; off; off >>= 1) s += __shfl_xor(s, off, 64);
    if ((threadIdx.x & 63) == 0) red[threadIdx.x >> 6] = s;
    __syncthreads();
    if (threadIdx.x == 0) bsum[blockIdx.x] = red[0] + red[1] + red[2] + red[3];
}

__global__ void k_bscan(const float* __restrict__ bsum, int* __restrict__ bofs,
                        int* __restrict__ row_ofs, int nb) {
    if (blockIdx.x == 0 && threadIdx.x == 0) {
        int run = 0;
        for (int i = 0; i < nb; ++i) { bofs[i] = run; run += (int)bsum[i]; }
        bofs[nb] = run;
        row_ofs[NN] = run;   // == NE
    }
}

__global__ void k_scan(const float* __restrict__ deg_in, const int* __restrict__ bofs,
                       int* __restrict__ row_ofs, int* __restrict__ cursor) {
    __shared__ int wofs[4];
    int t = threadIdx.x;
    int base = blockIdx.x * 1024 + t * 4;
    int d[4];
#pragma unroll
    for (int k = 0; k < 4; ++k) {
        int n = base + k;
        d[k] = (n < NN) ? (int)deg_in[n] : 0;
    }
    int loc = d[0] + d[1] + d[2] + d[3];
    int v = loc;
    int lane = t & 63;
#pragma unroll
    for (int off = 1; off < 64; off <<= 1) {
        int u = __shfl_up(v, off, 64);
        if (lane >= off) v += u;
    }
    if (lane == 63) wofs[t >> 6] = v;
    __syncthreads();
    int w = t >> 6;
    int wbase = 0;
    if (w > 0) wbase += wofs[0];
    if (w > 1) wbase += wofs[1];
    if (w > 2) wbase += wofs[2];
    int excl = bofs[blockIdx.x] + wbase + (v - loc);
#pragma unroll
    for (int k = 0; k < 4; ++k) {
        int n = base + k;
        if (n < NN) { row_ofs[n] = excl; cursor[n] = excl; excl += d[k]; }
    }
}

__global__ void k_fill(const int* __restrict__ src, const int* __restrict__ dst,
                       int* __restrict__ cursor, int* __restrict__ csr_src) {
    int e = blockIdx.x * blockDim.x + threadIdx.x;
    if (e < NE) {
        int pos = atomicAdd(&cursor[dst[e]], 1);
        csr_src[pos] = src[e];
    }
}

// ---------------- layer 1 aggregate + project + relu + W2-dot (fused) ----------------
// 512 threads = 8 waves = 8 nodes/block; lane = feature
__global__ void __launch_bounds__(512, 1)
k_agg1(const int* __restrict__ csr_src, const int* __restrict__ row_ofs,
       const float* __restrict__ x, const float* __restrict__ norm_out,
       const float* __restrict__ norm_in,
       const float* __restrict__ W1, const float* __restrict__ b1,
       const float* __restrict__ W2,
       float* __restrict__ z) {
    __shared__ float sW1[64 * 64];
    __shared__ float srow[8][64];
    int tid = threadIdx.x;
    for (int i = tid; i < 64 * 64; i += 512) sW1[i] = W1[i];
    int ni = tid >> 6;       // wave index (wave-uniform)
    int f  = tid & 63;       // feature = lane
    int n  = blockIdx.x * 8 + ni;
    float acc = 0.0f;
    if (n < NN) {
        int beg = row_ofs[n];
        int end = row_ofs[n + 1];
        int i = beg;
        for (; i + 3 < end; i += 4) {   // 4 outstanding row loads
            int s0 = csr_src[i], s1 = csr_src[i + 1], s2 = csr_src[i + 2], s3 = csr_src[i + 3];
            float a0 = x[(size_t)s0 * F + f] * norm_out[s0];
            float a1 = x[(size_t)s1 * F + f] * norm_out[s1];
            float a2 = x[(size_t)s2 * F + f] * norm_out[s2];
            float a3 = x[(size_t)s3 * F + f] * norm_out[s3];
            acc += (a0 + a1) + (a2 + a3);
        }
        for (; i < end; ++i) {
            int s = csr_src[i];
            acc += x[(size_t)s * F + f] * norm_out[s];
        }
    }
    srow[ni][f] = acc;
    __syncthreads();
    if (n < NN) {
        float p = 0.0f;
#pragma unroll
        for (int k = 0; k < 64; ++k)
            p += srow[ni][k] * sW1[k * 64 + f];   // broadcast + 2-way (free)
        float h = p * norm_in[n] + b1[f];
        h = fmaxf(h, 0.0f);
        float zv = h * W2[f];
#pragma unroll
        for (int off = 32; off; off >>= 1) zv += __shfl_xor(zv, off, 64);
        if (f == 0) z[n] = zv * norm_out[n];
    }
}

// ---------------- layer 2 gather + sigmoid ----------------
__global__ void k_out2(const int* __restrict__ csr_src, const int* __restrict__ row_ofs,
                       const float* __restrict__ z, const float* __restrict__ norm_in,
                       const float* __restrict__ b2, float* __restrict__ out) {
    int n = blockIdx.x * blockDim.x + threadIdx.x;
    if (n < NN) {
        int beg = row_ofs[n];
        int end = row_ofs[n + 1];
        float a = 0.0f;
        for (int i = beg; i < end; ++i) a += z[csr_src[i]];
        float v = a * norm_in[n] + b2[0];
        out[n] = 1.0f / (1.0f + expf(-v));
    }
}

// ---------------- launch ----------------

extern "C" void kernel_launch(void* const* d_in, const int* in_sizes, int n_in,
                              void* d_out, int out_size, void* d_ws, size_t ws_size,
                              hipStream_t stream) {
    const float* x   = (const float*)d_in[0];
    const int*   src = (const int*)d_in[1];
    const int*   dst = (const int*)d_in[2];
    const float* W1  = (const float*)d_in[3];
    const float* b1  = (const float*)d_in[4];
    const float* W2  = (const float*)d_in[5];
    const float* b2  = (const float*)d_in[6];
    float* out = (float*)d_out;

    // ws layout
    float* ws       = (float*)d_ws;
    float* deg_out  = ws;                 // NN
    float* deg_in   = ws + NN;            // NN
    float* norm_out = ws + 2 * NN;        // NN
    float* norm_in  = ws + 3 * NN;        // NN
    float* z        = ws + 4 * NN;        // NN
    float* bsum     = ws + 5 * NN;        // 128
    int*   bofs     = (int*)(ws + 5 * NN + 128);   // 128
    int*   row_ofs  = bofs + 128;         // NN+1
    int*   cursor   = row_ofs + NN + 1;   // NN
    int*   csr_src  = cursor + NN;        // NE

    // zero only the atomically-accumulated degree arrays
    hipMemsetAsync(deg_out, 0, 2 * (size_t)NN * sizeof(float), stream);

    int nb = (NN + 1023) / 1024;   // 98

    k_deg  <<<(NE + 255) / 256, 256, 0, stream>>>(src, dst, deg_out, deg_in);
    k_norm <<<(NN + 255) / 256, 256, 0, stream>>>(deg_out, deg_in, norm_out, norm_in);
    k_bsum <<<nb, 256, 0, stream>>>(deg_in, bsum);
    k_bscan<<<1, 64, 0, stream>>>(bsum, bofs, row_ofs, nb);
    k_scan <<<nb, 256, 0, stream>>>(deg_in, bofs, row_ofs, cursor);
    k_fill <<<(NE + 255) / 256, 256, 0, stream>>>(src, dst, cursor, csr_src);

    k_agg1 <<<(NN + 7) / 8, 512, 0, stream>>>(csr_src, row_ofs, x, norm_out, norm_in,
                                              W1, b1, W2, z);
    k_out2 <<<(NN + 255) / 256, 256, 0, stream>>>(csr_src, row_ofs, z, norm_in, b2, out);
}

// Round 3
// 328.185 us; speedup vs baseline: 2.0199x; 1.2743x over previous
//
#include <hip/hip_runtime.h>

#define NN 100000
#define NE 1600000
#define F 64
#define SP 3   // log2(spread): one counter per 32B sector

// ---------------- count degrees (spread counters) + edge rank ----------------

__global__ void k_count(const int* __restrict__ src, const int* __restrict__ dst,
                        int* __restrict__ cnt_out, int* __restrict__ cnt_in,
                        int* __restrict__ rank) {
    int e = blockIdx.x * blockDim.x + threadIdx.x;
    if (e < NE) {
        atomicAdd(&cnt_out[src[e] << SP], 1);
        rank[e] = atomicAdd(&cnt_in[dst[e] << SP], 1);
    }
}

__global__ void k_norm(const int* __restrict__ cnt_out, const int* __restrict__ cnt_in,
                       float* __restrict__ norm_out, float* __restrict__ norm_in) {
    int n = blockIdx.x * blockDim.x + threadIdx.x;
    if (n < NN) {
        float d_o = (float)cnt_out[n << SP];
        float d_i = (float)cnt_in[n << SP];
        norm_out[n] = (d_o > 0.0f) ? rsqrtf(d_o) : 1.0f;
        norm_in[n]  = (d_i > 0.0f) ? rsqrtf(d_i) : 1.0f;
    }
}

// ---------------- CSR row offsets: prefix sum of cnt_in ----------------

__global__ void k_bsum(const int* __restrict__ cnt_in, int* __restrict__ bsum) {
    __shared__ int red[4];
    int base = blockIdx.x * 1024;
    int s = 0;
    for (int i = threadIdx.x; i < 1024; i += 256) {
        int n = base + i;
        s += (n < NN) ? cnt_in[n << SP] : 0;
    }
#pragma unroll
    for (int off = 32; off; off >>= 1) s += __shfl_xor(s, off, 64);
    if ((threadIdx.x & 63) == 0) red[threadIdx.x >> 6] = s;
    __syncthreads();
    if (threadIdx.x == 0) bsum[blockIdx.x] = red[0] + red[1] + red[2] + red[3];
}

__global__ void k_bscan(const int* __restrict__ bsum, int* __restrict__ bofs,
                        int* __restrict__ row_ofs, int nb) {
    if (blockIdx.x == 0 && threadIdx.x == 0) {
        int run = 0;
        for (int i = 0; i < nb; ++i) { bofs[i] = run; run += bsum[i]; }
        bofs[nb] = run;
        row_ofs[NN] = run;   // == NE
    }
}

__global__ void k_scan(const int* __restrict__ cnt_in, const int* __restrict__ bofs,
                       int* __restrict__ row_ofs) {
    __shared__ int wofs[4];
    int t = threadIdx.x;
    int base = blockIdx.x * 1024 + t * 4;
    int d[4];
#pragma unroll
    for (int k = 0; k < 4; ++k) {
        int n = base + k;
        d[k] = (n < NN) ? cnt_in[n << SP] : 0;
    }
    int loc = d[0] + d[1] + d[2] + d[3];
    int v = loc;
    int lane = t & 63;
#pragma unroll
    for (int off = 1; off < 64; off <<= 1) {
        int u = __shfl_up(v, off, 64);
        if (lane >= off) v += u;
    }
    if (lane == 63) wofs[t >> 6] = v;
    __syncthreads();
    int w = t >> 6;
    int wbase = 0;
    if (w > 0) wbase += wofs[0];
    if (w > 1) wbase += wofs[1];
    if (w > 2) wbase += wofs[2];
    int excl = bofs[blockIdx.x] + wbase + (v - loc);
#pragma unroll
    for (int k = 0; k < 4; ++k) {
        int n = base + k;
        if (n < NN) { row_ofs[n] = excl; excl += d[k]; }
    }
}

// ---------------- atomic-free CSR fill using precomputed ranks ----------------

__global__ void k_fill2(const int* __restrict__ src, const int* __restrict__ dst,
                        const int* __restrict__ rank, const int* __restrict__ row_ofs,
                        int* __restrict__ csr_src) {
    int e = blockIdx.x * blockDim.x + threadIdx.x;
    if (e < NE) {
        csr_src[row_ofs[dst[e]] + rank[e]] = src[e];
    }
}

// ---------------- layer 1 aggregate + project + relu + W2-dot (fused) ----------------
// 512 threads = 8 waves = 8 nodes/block; two 32-lane halves each gather a
// different edge's x-row as float2 (8B/lane), combined by one shfl_xor(32).
__global__ void __launch_bounds__(512, 1)
k_agg1(const int* __restrict__ csr_src, const int* __restrict__ row_ofs,
       const float* __restrict__ x, const float* __restrict__ norm_out,
       const float* __restrict__ norm_in,
       const float* __restrict__ W1, const float* __restrict__ b1,
       const float* __restrict__ W2,
       float* __restrict__ z) {
    __shared__ float sW1[64 * 64];
    __shared__ float srow[8][64];
    int tid = threadIdx.x;
    for (int i = tid; i < 64 * 64; i += 512) sW1[i] = W1[i];
    int ni   = tid >> 6;      // wave index (wave-uniform)
    int lane = tid & 63;
    int half = lane >> 5;     // which edge of the pair this lane gathers
    int lh   = lane & 31;     // float2 index within the row
    int n    = blockIdx.x * 8 + ni;
    float ax = 0.0f, ay = 0.0f;
    if (n < NN) {
        int beg = row_ofs[n];
        int end = row_ofs[n + 1];
        int i = beg;
        for (; i + 3 < end; i += 4) {          // 4 edges in flight
            int sa = csr_src[i + half];
            int sb = csr_src[i + 2 + half];
            float na = norm_out[sa];
            float nb = norm_out[sb];
            float2 va = *(const float2*)&x[((size_t)sa << 6) + (lh << 1)];
            float2 vb = *(const float2*)&x[((size_t)sb << 6) + (lh << 1)];
            ax += va.x * na + vb.x * nb;
            ay += va.y * na + vb.y * nb;
        }
        for (; i + 1 < end; i += 2) {          // 2 edges
            int sa = csr_src[i + half];
            float na = norm_out[sa];
            float2 va = *(const float2*)&x[((size_t)sa << 6) + (lh << 1)];
            ax += va.x * na;
            ay += va.y * na;
        }
        if (i < end && half == 0) {            // tail edge: half-0 lanes only
            int sa = csr_src[i];
            float na = norm_out[sa];
            float2 va = *(const float2*)&x[((size_t)sa << 6) + (lh << 1)];
            ax += va.x * na;
            ay += va.y * na;
        }
    }
    ax += __shfl_xor(ax, 32, 64);
    ay += __shfl_xor(ay, 32, 64);
    if (half == 0) {
        srow[ni][(lh << 1)]     = ax;
        srow[ni][(lh << 1) + 1] = ay;
    }
    __syncthreads();
    if (n < NN) {
        float p = 0.0f;
#pragma unroll
        for (int k = 0; k < 64; ++k)
            p += srow[ni][k] * sW1[k * 64 + lane];   // broadcast + linear banks
        float h = p * norm_in[n] + b1[lane];
        h = fmaxf(h, 0.0f);
        float zv = h * W2[lane];
#pragma unroll
        for (int off = 32; off; off >>= 1) zv += __shfl_xor(zv, off, 64);
        if (lane == 0) z[n] = zv * norm_out[n];
    }
}

// ---------------- layer 2 gather + sigmoid ----------------
__global__ void k_out2(const int* __restrict__ csr_src, const int* __restrict__ row_ofs,
                       const float* __restrict__ z, const float* __restrict__ norm_in,
                       const float* __restrict__ b2, float* __restrict__ out) {
    int n = blockIdx.x * blockDim.x + threadIdx.x;
    if (n < NN) {
        int beg = row_ofs[n];
        int end = row_ofs[n + 1];
        float a = 0.0f;
        for (int i = beg; i < end; ++i) a += z[csr_src[i]];
        float v = a * norm_in[n] + b2[0];
        out[n] = 1.0f / (1.0f + expf(-v));
    }
}

// ---------------- launch ----------------

extern "C" void kernel_launch(void* const* d_in, const int* in_sizes, int n_in,
                              void* d_out, int out_size, void* d_ws, size_t ws_size,
                              hipStream_t stream) {
    const float* x   = (const float*)d_in[0];
    const int*   src = (const int*)d_in[1];
    const int*   dst = (const int*)d_in[2];
    const float* W1  = (const float*)d_in[3];
    const float* b1  = (const float*)d_in[4];
    const float* W2  = (const float*)d_in[5];
    const float* b2  = (const float*)d_in[6];
    float* out = (float*)d_out;

    // ws layout (4B units)
    int*   cnt_out  = (int*)d_ws;                       // NN<<SP  (3.2 MB)
    int*   cnt_in   = cnt_out + ((size_t)NN << SP);     // NN<<SP  (3.2 MB)
    float* norm_out = (float*)(cnt_in + ((size_t)NN << SP));  // NN
    float* norm_in  = norm_out + NN;                    // NN
    float* z        = norm_in + NN;                     // NN
    int*   bsum     = (int*)(z + NN);                   // 128
    int*   bofs     = bsum + 128;                       // 129
    int*   row_ofs  = bofs + 129;                       // NN+1
    int*   rank     = row_ofs + NN + 1;                 // NE
    int*   csr_src  = rank + NE;                        // NE

    // zero the two spread counter arrays (contiguous at ws start)
    hipMemsetAsync(d_ws, 0, 2 * (((size_t)NN << SP) * sizeof(int)), stream);

    int nb = (NN + 1023) / 1024;   // 98

    k_count<<<(NE + 255) / 256, 256, 0, stream>>>(src, dst, cnt_out, cnt_in, rank);
    k_norm <<<(NN + 255) / 256, 256, 0, stream>>>(cnt_out, cnt_in, norm_out, norm_in);
    k_bsum <<<nb, 256, 0, stream>>>(cnt_in, bsum);
    k_bscan<<<1, 64, 0, stream>>>(bsum, bofs, row_ofs, nb);
    k_scan <<<nb, 256, 0, stream>>>(cnt_in, bofs, row_ofs);
    k_fill2<<<(NE + 255) / 256, 256, 0, stream>>>(src, dst, rank, row_ofs, csr_src);

    k_agg1 <<<(NN + 7) / 8, 512, 0, stream>>>(csr_src, row_ofs, x, norm_out, norm_in,
                                              W1, b1, W2, z);
    k_out2 <<<(NN + 255) / 256, 256, 0, stream>>>(csr_src, row_ofs, z, norm_in, b2, out);
}

// Round 4
// 200.441 us; speedup vs baseline: 3.3071x; 1.6373x over previous
//
#include <hip/hip_runtime.h>

#define NN 100000
#define NE 1600000
#define NW 25000          // NN/4 packed-byte words
#define S  64             // edge slices
#define EPS (NE / S)      // 25000 edges per slice

typedef unsigned int uint;

// ---------------- packed-byte LDS histogram over ALL nodes (100KB LDS) ----------------
// grid (S, 2): y=0 counts dst (and records local rank), y=1 counts src
__global__ void __launch_bounds__(256)
k_hist(const int* __restrict__ src, const int* __restrict__ dst,
       uint* __restrict__ partial_in, uint* __restrict__ partial_out,
       unsigned char* __restrict__ lr) {
    __shared__ uint cnt[NW];          // 100,000 B = packed byte counters for all nodes
    int sl = blockIdx.x;
    int y  = blockIdx.y;
    for (int w = threadIdx.x; w < NW; w += 256) cnt[w] = 0;
    __syncthreads();
    const int* key = y ? src : dst;
    int base = sl * EPS;
    for (int i = threadIdx.x; i < EPS; i += 256) {
        int e = base + i;
        int k = key[e];
        uint sh = (uint)(k & 3) * 8u;
        uint old = atomicAdd(&cnt[k >> 2], 1u << sh);
        if (y == 0) lr[e] = (unsigned char)((old >> sh) & 0xffu);
    }
    __syncthreads();
    uint* dp = (y ? partial_out : partial_in) + (size_t)sl * NW;
    for (int w = threadIdx.x; w < NW; w += 256) dp[w] = cnt[w];
}

// ---------------- byte-SIMD prefix over slices + degrees + norms ----------------
// thread = one packed word (4 nodes). partial_in is overwritten in-place with
// the per-slice exclusive byte-prefix (base_local). Carry-free: all byte sums <= degree <= 255.
__global__ void k_degnorm(uint* __restrict__ partial_in, const uint* __restrict__ partial_out,
                          int* __restrict__ deg_in, float* __restrict__ norm_in,
                          float* __restrict__ norm_out) {
    int w = blockIdx.x * blockDim.x + threadIdx.x;
    if (w >= NW) return;
    uint run = 0;
#pragma unroll 8
    for (int s = 0; s < S; ++s) {
        uint u = partial_in[(size_t)s * NW + w];
        partial_in[(size_t)s * NW + w] = run;
        run += u;
    }
    uint ro = 0;
#pragma unroll 8
    for (int s = 0; s < S; ++s) ro += partial_out[(size_t)s * NW + w];
    int4 dg;
    float4 fi, fo;
    {
        int d0 = run & 0xff, d1 = (run >> 8) & 0xff, d2 = (run >> 16) & 0xff, d3 = (run >> 24) & 0xff;
        dg = make_int4(d0, d1, d2, d3);
        fi.x = d0 > 0 ? rsqrtf((float)d0) : 1.0f;
        fi.y = d1 > 0 ? rsqrtf((float)d1) : 1.0f;
        fi.z = d2 > 0 ? rsqrtf((float)d2) : 1.0f;
        fi.w = d3 > 0 ? rsqrtf((float)d3) : 1.0f;
        int o0 = ro & 0xff, o1 = (ro >> 8) & 0xff, o2 = (ro >> 16) & 0xff, o3 = (ro >> 24) & 0xff;
        fo.x = o0 > 0 ? rsqrtf((float)o0) : 1.0f;
        fo.y = o1 > 0 ? rsqrtf((float)o1) : 1.0f;
        fo.z = o2 > 0 ? rsqrtf((float)o2) : 1.0f;
        fo.w = o3 > 0 ? rsqrtf((float)o3) : 1.0f;
    }
    *(int4*)&deg_in[w * 4]    = dg;
    *(float4*)&norm_in[w * 4]  = fi;
    *(float4*)&norm_out[w * 4] = fo;
}

// ---------------- row_ofs: exclusive scan of deg_in ----------------

__global__ void k_bsum(const int* __restrict__ deg_in, int* __restrict__ bsum) {
    __shared__ int red[4];
    int base = blockIdx.x * 1024;
    int s = 0;
    for (int i = threadIdx.x; i < 1024; i += 256) {
        int n = base + i;
        s += (n < NN) ? deg_in[n] : 0;
    }
#pragma unroll
    for (int off = 32; off; off >>= 1) s += __shfl_xor(s, off, 64);
    if ((threadIdx.x & 63) == 0) red[threadIdx.x >> 6] = s;
    __syncthreads();
    if (threadIdx.x == 0) bsum[blockIdx.x] = red[0] + red[1] + red[2] + red[3];
}

__global__ void k_bscan(const int* __restrict__ bsum, int* __restrict__ bofs,
                        int* __restrict__ row_ofs, int nb) {
    if (blockIdx.x == 0 && threadIdx.x == 0) {
        int run = 0;
        for (int i = 0; i < nb; ++i) { bofs[i] = run; run += bsum[i]; }
        bofs[nb] = run;
        row_ofs[NN] = run;   // == NE
    }
}

__global__ void k_scan(const int* __restrict__ deg_in, const int* __restrict__ bofs,
                       int* __restrict__ row_ofs) {
    __shared__ int wofs[4];
    int t = threadIdx.x;
    int base = blockIdx.x * 1024 + t * 4;
    int d[4];
#pragma unroll
    for (int k = 0; k < 4; ++k) {
        int n = base + k;
        d[k] = (n < NN) ? deg_in[n] : 0;
    }
    int loc = d[0] + d[1] + d[2] + d[3];
    int v = loc;
    int lane = t & 63;
#pragma unroll
    for (int off = 1; off < 64; off <<= 1) {
        int u = __shfl_up(v, off, 64);
        if (lane >= off) v += u;
    }
    if (lane == 63) wofs[t >> 6] = v;
    __syncthreads();
    int w = t >> 6;
    int wbase = 0;
    if (w > 0) wbase += wofs[0];
    if (w > 1) wbase += wofs[1];
    if (w > 2) wbase += wofs[2];
    int excl = bofs[blockIdx.x] + wbase + (v - loc);
#pragma unroll
    for (int k = 0; k < 4; ++k) {
        int n = base + k;
        if (n < NN) { row_ofs[n] = excl; excl += d[k]; }
    }
}

// ---------------- atomic-free CSR fill ----------------
__global__ void k_replay(const int* __restrict__ src, const int* __restrict__ dst,
                         const uint* __restrict__ base_bytes, const unsigned char* __restrict__ lr,
                         const int* __restrict__ row_ofs, int* __restrict__ csr_src) {
    int e = blockIdx.x * blockDim.x + threadIdx.x;
    if (e < NE) {
        int d  = dst[e];
        int sl = e / EPS;
        uint pw = base_bytes[(size_t)sl * NW + (d >> 2)];
        int b = (int)((pw >> ((d & 3) * 8)) & 0xffu);
        csr_src[row_ofs[d] + b + (int)lr[e]] = src[e];
    }
}

// ---------------- pre-scaled bf16 features: xb = bf16(x * norm_out) ----------------
__device__ inline uint bfpair(float a, float b) {   // two RNE bf16 packed in a uint
    uint ua = __float_as_uint(a); ua += 0x7fffu + ((ua >> 16) & 1u);
    uint ub = __float_as_uint(b); ub += 0x7fffu + ((ub >> 16) & 1u);
    return (ua >> 16) | (ub & 0xffff0000u);
}

__global__ void k_cvt(const float* __restrict__ x, const float* __restrict__ norm_out,
                      uint* __restrict__ xb) {
    int t = blockIdx.x * blockDim.x + threadIdx.x;
    if (t < NN * 16) {
        int node = t >> 4, j = t & 15;
        float no = norm_out[node];
        float4 v = *(const float4*)&x[(size_t)node * 64 + j * 4];
        uint2 p;
        p.x = bfpair(v.x * no, v.y * no);
        p.y = bfpair(v.z * no, v.w * no);
        *(uint2*)&xb[(size_t)t * 2] = p;
    }
}

// ---------------- layer 1 aggregate (bf16 gather) + project + relu + W2-dot ----------------
// 512 thr = 8 waves = 8 nodes/block. Wave splits into 4 quarters of 16 lanes;
// each quarter gathers a different edge's 128B row (uint2 = 4 bf16 per lane).
__global__ void __launch_bounds__(512)
k_agg1(const int* __restrict__ csr_src, const int* __restrict__ row_ofs,
       const uint* __restrict__ xb, const float* __restrict__ norm_in,
       const float* __restrict__ norm_out,
       const float* __restrict__ W1, const float* __restrict__ b1,
       const float* __restrict__ W2, float* __restrict__ z) {
    __shared__ float sW1[64 * 64];
    __shared__ float srow[8][64];
    int tid = threadIdx.x;
    for (int i = tid; i < 4096; i += 512) sW1[i] = W1[i];
    int ni = tid >> 6, lane = tid & 63, q = lane >> 4, lq = lane & 15;
    int n = blockIdx.x * 8 + ni;
    if (n < NN) {
        float a0 = 0, a1 = 0, a2 = 0, a3 = 0;
        int beg = row_ofs[n], end = row_ofs[n + 1];
        for (int ei = beg + q; ei < end; ei += 4) {
            int s = csr_src[ei];
            uint2 u = *(const uint2*)((const char*)xb + ((size_t)s << 7) + (lq << 3));
            a0 += __uint_as_float(u.x << 16);
            a1 += __uint_as_float(u.x & 0xffff0000u);
            a2 += __uint_as_float(u.y << 16);
            a3 += __uint_as_float(u.y & 0xffff0000u);
        }
        a0 += __shfl_xor(a0, 16, 64); a0 += __shfl_xor(a0, 32, 64);
        a1 += __shfl_xor(a1, 16, 64); a1 += __shfl_xor(a1, 32, 64);
        a2 += __shfl_xor(a2, 16, 64); a2 += __shfl_xor(a2, 32, 64);
        a3 += __shfl_xor(a3, 16, 64); a3 += __shfl_xor(a3, 32, 64);
        if (q == 0) {
            float4 r = make_float4(a0, a1, a2, a3);
            *(float4*)&srow[ni][lq << 2] = r;
        }
    }
    __syncthreads();
    if (n < NN) {
        float p = 0.0f;
#pragma unroll
        for (int k = 0; k < 64; ++k)
            p += srow[ni][k] * sW1[k * 64 + lane];
        float h = fmaxf(p * norm_in[n] + b1[lane], 0.0f);
        float zv = h * W2[lane];
#pragma unroll
        for (int off = 32; off; off >>= 1) zv += __shfl_xor(zv, off, 64);
        if (lane == 0) z[n] = zv * norm_out[n];
    }
}

// ---------------- layer 2 gather + sigmoid ----------------
__global__ void k_out2(const int* __restrict__ csr_src, const int* __restrict__ row_ofs,
                       const float* __restrict__ z, const float* __restrict__ norm_in,
                       const float* __restrict__ b2, float* __restrict__ out) {
    int n = blockIdx.x * blockDim.x + threadIdx.x;
    if (n < NN) {
        int beg = row_ofs[n], end = row_ofs[n + 1];
        float a = 0.0f;
        int i = beg;
        for (; i + 3 < end; i += 4) {
            float z0 = z[csr_src[i]], z1 = z[csr_src[i + 1]];
            float z2 = z[csr_src[i + 2]], z3 = z[csr_src[i + 3]];
            a += (z0 + z1) + (z2 + z3);
        }
        for (; i < end; ++i) a += z[csr_src[i]];
        float v = a * norm_in[n] + b2[0];
        out[n] = 1.0f / (1.0f + expf(-v));
    }
}

// ---------------- launch ----------------

extern "C" void kernel_launch(void* const* d_in, const int* in_sizes, int n_in,
                              void* d_out, int out_size, void* d_ws, size_t ws_size,
                              hipStream_t stream) {
    const float* x   = (const float*)d_in[0];
    const int*   src = (const int*)d_in[1];
    const int*   dst = (const int*)d_in[2];
    const float* W1  = (const float*)d_in[3];
    const float* b1  = (const float*)d_in[4];
    const float* W2  = (const float*)d_in[5];
    const float* b2  = (const float*)d_in[6];
    float* out = (float*)d_out;

    // ws layout (4B words). xb (3.2M words) aliases partial_in+lr+partial_out,
    // which are all dead after k_replay; k_cvt runs after k_replay.
    uint* W0 = (uint*)d_ws;
    uint*          partial_in  = W0;                                  // 1.6M words
    unsigned char* lr          = (unsigned char*)(W0 + 1600000);      // 400K words
    uint*          partial_out = W0 + 2000000;                        // 1.6M words
    uint*          xb          = W0;                                  // 3.2M words (phase B)
    int*           csr_src     = (int*)(W0 + 3600000);                // 1.6M words
    int*           row_ofs     = (int*)(W0 + 5200000);                // NN+1
    int*           deg_in      = row_ofs + NN + 32;                   // NN
    float*         norm_in     = (float*)(deg_in + NN);               // NN
    float*         norm_out    = norm_in + NN;                        // NN
    float*         z           = norm_out + NN;                       // NN
    int*           bsum        = (int*)(z + NN);                      // 98
    int*           bofs        = bsum + 128;                          // 99

    int nb = (NN + 1023) / 1024;   // 98

    k_hist   <<<dim3(S, 2), 256, 0, stream>>>(src, dst, partial_in, partial_out, lr);
    k_degnorm<<<(NW + 255) / 256, 256, 0, stream>>>(partial_in, partial_out,
                                                    deg_in, norm_in, norm_out);
    k_bsum   <<<nb, 256, 0, stream>>>(deg_in, bsum);
    k_bscan  <<<1, 64, 0, stream>>>(bsum, bofs, row_ofs, nb);
    k_scan   <<<nb, 256, 0, stream>>>(deg_in, bofs, row_ofs);
    k_replay <<<(NE + 255) / 256, 256, 0, stream>>>(src, dst, partial_in, lr, row_ofs, csr_src);

    k_cvt    <<<(NN * 16 + 255) / 256, 256, 0, stream>>>(x, norm_out, xb);
    k_agg1   <<<(NN + 7) / 8, 512, 0, stream>>>(csr_src, row_ofs, xb, norm_in, norm_out,
                                                W1, b1, W2, z);
    k_out2   <<<(NN + 255) / 256, 256, 0, stream>>>(csr_src, row_ofs, z, norm_in, b2, out);
}